// Round 10
// baseline (198.873 us; speedup 1.0000x reference)
//
#include <hip/hip_runtime.h>
#include <math.h>

// ---------------------------------------------------------------------------
// Decoder_82764019794508: LIIF-style decoder.
// R29: fused_front conv diet. R28's 32x32 decoder landed (total 203->193,
// decoder out of top-5); front is now the largest kernel: 44.6us at
// VALUBusy 11.5%, HBM 7% -> vmem-ISSUE-bound: each conv1x1 thread re-loads
// 4 weight float4 per K-step (64 w-loads vs 16 x-loads per thread, 80:256
// load:FMA). Fix: 4 pixels/thread — weights loaded once per K-step and
// applied to 4 x rows: loads/px 80->32 (-60%), FMA:load 8:1, 4 independent
// acc chains. Accumulation order per output unchanged (i4 outer, j inner)
// -> BIT-IDENTICAL output (absmax must stay 0.0002441406). Grid 1029->483.
// K2/K3/K4 = R28 verbatim (32x32x16 decoder, 8 q/wave, proven).
// ---------------------------------------------------------------------------

#define HQ 384
#define HA 192
#define NQ (2 * HQ * HQ)   // 294912 queries
#define NBS (NQ / 1024)    // 288 sort blocks (1024 threads each)
#define NBKT 288           // 2 batches x 12x12 tiles of 16x16 px
#define NFLAT (NBKT * NBS) // 82944 = 81 * 1024

typedef _Float16 half8  __attribute__((ext_vector_type(8)));
typedef _Float16 half4v __attribute__((ext_vector_type(4)));
typedef float    float4v __attribute__((ext_vector_type(4)));
typedef float    float16v __attribute__((ext_vector_type(16)));

// bucket id from query coords: corner k=0 (vy=vx=-1) pixel, 16x16 tiles
__device__ __forceinline__ int bucket_id(int q, float cy, float cx) {
    const float LO = -1.0f + 1e-7f, HI = 1.0f - 1e-7f;
    const float RXY = 1.0f / (float)HA;
    float c0 = fminf(fmaxf((cy - RXY) + 1e-7f, LO), HI);
    float c1 = fminf(fmaxf((cx - RXY) + 1e-7f, LO), HI);
    int iy = (int)rintf(((c0 + 1.f) * (float)HA) * 0.5f - 0.5f);
    int ix = (int)rintf(((c1 + 1.f) * (float)HA) * 0.5f - 0.5f);
    iy = min(max(iy, 0), HA - 1);
    ix = min(max(ix, 0), HA - 1);
    int b = q / (HQ * HQ);
    return b * 144 + (iy >> 4) * 12 + (ix >> 4);
}

// ===========================================================================
// K1: fused_front — sort_count | prep frags (32x32 tables) | conv1x1 x3 | xcat
// Conv paths: 4 px/thread, weights amortized. Grid 483 blocks:
//   0..287 sort | 288..299 tables | 300..335 a4 | 336..338 a32 | 339..482 f2
// ===========================================================================
__launch_bounds__(1024)
__global__ void fused_front(const float* __restrict__ coords,
                            int* __restrict__ cntT,
                            unsigned short* __restrict__ lrank,
                            const float* __restrict__ mw0,
                            const float* __restrict__ mb0f,
                            const float* __restrict__ mw1,
                            const float* __restrict__ mb1f,
                            const float* __restrict__ wf,
                            _Float16* __restrict__ fragTab,
                            _Float16* __restrict__ fragTabW,
                            const float* __restrict__ feats4,
                            const float* __restrict__ w4,
                            const float* __restrict__ b4,
                            const float* __restrict__ feats32,
                            const float* __restrict__ w32,
                            const float* __restrict__ b32,
                            float* __restrict__ a4s,
                            float* __restrict__ a32s,
                            const float* __restrict__ feats2,
                            const float* __restrict__ w2,
                            const float* __restrict__ b2,
                            _Float16* __restrict__ xcatH) {
    const int blk = blockIdx.x;
    const int tid = threadIdx.x;

    if (blk < 288) {
        __shared__ int lh[NBKT];
        if (tid < NBKT) lh[tid] = 0;
        __syncthreads();
        const int q = blk * 1024 + tid;
        float cy = coords[(size_t)q * 2 + 0];
        float cx = coords[(size_t)q * 2 + 1];
        int r = atomicAdd(&lh[bucket_id(q, cy, cx)], 1);
        lrank[q] = (unsigned short)r;
        __syncthreads();
        if (tid < NBKT) cntT[tid * NBS + blk] = lh[tid];
    } else if (blk < 300) {
        int t = (blk - 288) * 1024 + tid;
        if (t < 1536) {
            // 24 fragments x 64 lanes: f 0..13 = W0 (ks 0..6, nt 0..1),
            // f 14..23 = W1 (ks 0..4, nt 0..1). A-operand layout for
            // 32x32x16: row = lane&31, k = (lane>>5)*8 + j.
            int f = t >> 6, L = t & 63;
            int h = L >> 5;
            _Float16 vals[8];
            if (f < 14) {
                int ks = f >> 1, nt = f & 1;
                int col = nt * 32 + (L & 31);
#pragma unroll
                for (int j = 0; j < 8; ++j) {
                    int kk = ks * 16 + h * 8 + j;
                    float v = (kk < 102) ? mw0[kk * 64 + col]
                            : ((kk == 102) ? mb0f[col] : 0.f);
                    vals[j] = (_Float16)v;
                }
            } else {
                // W1 with ROW PERMUTATION: physical k-slot kp holds logical
                // row n = kp with bits 3<->2 swapped, so layer1 B-frags are
                // b1[ks][j] = relu(acc[ks>>1][(ks&1)*8+j]) straight from the
                // layer0 accumulator. ks=4 (k 64..79): row 64 = mb1, rest 0.
                int g = f - 14;
                int ks = g >> 1, nt = g & 1;
                int col = nt * 32 + (L & 31);
#pragma unroll
                for (int j = 0; j < 8; ++j) {
                    int kp = ks * 16 + h * 8 + j;
                    float v;
                    if (ks < 4) {
                        int n = (kp & 0x33) | ((kp & 8) >> 1) | ((kp & 4) << 1);
                        v = mw1[n * 64 + col];
                    } else {
                        v = (kp == 64) ? mb1f[col] : 0.f;
                    }
                    vals[j] = (_Float16)v;
                }
            }
#pragma unroll
            for (int j = 0; j < 8; ++j) fragTab[t * 8 + j] = vals[j];
        } else {
            int tw = t - 1536;
            if (tw < 27 * 6 * 64) {
                int s   = tw / 384;
                int rem = tw - s * 384;
                int nt  = rem >> 6;
                int L   = rem & 63;
                int n_  = L & 15, qd = L >> 4;
                int tap = s / 3, kc = s - tap * 3;
#pragma unroll
                for (int j = 0; j < 8; ++j) {
                    int kch = kc * 32 + qd * 8 + j;
                    fragTabW[tw * 8 + j] =
                        (_Float16)wf[(tap * 96 + kch) * 96 + nt * 16 + n_];
                }
            }
        }
    } else if (blk < 336) {
        // a4 conv1x1: 18432 px, 4 px/thread, 8 cg -> 36864 threads
        int t = (blk - 300) * 1024 + tid;
        int pg = t >> 3, cg = t & 7;
        int p0 = pg * 4;
        float4v bv = *(const float4v*)(b4 + cg * 4);
        float4v acc[4] = {bv, bv, bv, bv};
#pragma unroll
        for (int i4 = 0; i4 < 24; ++i4) {
            const float* wr = w4 + (i4 * 4) * 32 + cg * 4;
            float4v wv[4];
#pragma unroll
            for (int j = 0; j < 4; ++j) wv[j] = *(const float4v*)(wr + j * 32);
#pragma unroll
            for (int u = 0; u < 4; ++u) {
                float4v xv = ((const float4v*)(feats4 + (size_t)(p0 + u) * 96))[i4];
#pragma unroll
                for (int j = 0; j < 4; ++j) {
                    acc[u][0] = fmaf(xv[j], wv[j][0], acc[u][0]);
                    acc[u][1] = fmaf(xv[j], wv[j][1], acc[u][1]);
                    acc[u][2] = fmaf(xv[j], wv[j][2], acc[u][2]);
                    acc[u][3] = fmaf(xv[j], wv[j][3], acc[u][3]);
                }
            }
        }
#pragma unroll
        for (int u = 0; u < 4; ++u) {
            float4v o = {fmaxf(acc[u][0], 0.f), fmaxf(acc[u][1], 0.f),
                         fmaxf(acc[u][2], 0.f), fmaxf(acc[u][3], 0.f)};
            *(float4v*)(a4s + (size_t)(p0 + u) * 32 + cg * 4) = o;
        }
    } else if (blk < 339) {
        // a32 conv1x1: 1152 px, 4 px/thread, 8 cg -> 2304 threads
        int t = (blk - 336) * 1024 + tid;
        if (t >= 2304) return;
        int pg = t >> 3, cg = t & 7;
        int p0 = pg * 4;
        float4v bv = *(const float4v*)(b32 + cg * 4);
        float4v acc[4] = {bv, bv, bv, bv};
#pragma unroll
        for (int i4 = 0; i4 < 40; ++i4) {
            const float* wr = w32 + (i4 * 4) * 32 + cg * 4;
            float4v wv[4];
#pragma unroll
            for (int j = 0; j < 4; ++j) wv[j] = *(const float4v*)(wr + j * 32);
#pragma unroll
            for (int u = 0; u < 4; ++u) {
                float4v xv = ((const float4v*)(feats32 + (size_t)(p0 + u) * 160))[i4];
#pragma unroll
                for (int j = 0; j < 4; ++j) {
                    acc[u][0] = fmaf(xv[j], wv[j][0], acc[u][0]);
                    acc[u][1] = fmaf(xv[j], wv[j][1], acc[u][1]);
                    acc[u][2] = fmaf(xv[j], wv[j][2], acc[u][2]);
                    acc[u][3] = fmaf(xv[j], wv[j][3], acc[u][3]);
                }
            }
        }
#pragma unroll
        for (int u = 0; u < 4; ++u) {
            float4v o = {fmaxf(acc[u][0], 0.f), fmaxf(acc[u][1], 0.f),
                         fmaxf(acc[u][2], 0.f), fmaxf(acc[u][3], 0.f)};
            *(float4v*)(a32s + (size_t)(p0 + u) * 32 + cg * 4) = o;
        }
    } else {
        // feats2 conv1x1 -> xcat z0: 73728 px, 4 px/thread, 8 cg
        int t = (blk - 339) * 1024 + tid;
        int pg = t >> 3, cg = t & 7;
        int p0 = pg * 4;
        float4v bv = *(const float4v*)(b2 + cg * 4);
        float4v acc[4] = {bv, bv, bv, bv};
#pragma unroll
        for (int i4 = 0; i4 < 16; ++i4) {
            const float* wr = w2 + (i4 * 4) * 32 + cg * 4;
            float4v wv[4];
#pragma unroll
            for (int j = 0; j < 4; ++j) wv[j] = *(const float4v*)(wr + j * 32);
#pragma unroll
            for (int u = 0; u < 4; ++u) {
                float4v xv = ((const float4v*)(feats2 + (size_t)(p0 + u) * 64))[i4];
#pragma unroll
                for (int j = 0; j < 4; ++j) {
                    acc[u][0] = fmaf(xv[j], wv[j][0], acc[u][0]);
                    acc[u][1] = fmaf(xv[j], wv[j][1], acc[u][1]);
                    acc[u][2] = fmaf(xv[j], wv[j][2], acc[u][2]);
                    acc[u][3] = fmaf(xv[j], wv[j][3], acc[u][3]);
                }
            }
        }
#pragma unroll
        for (int u = 0; u < 4; ++u) {
            half4v h;
            h[0] = (_Float16)fmaxf(acc[u][0], 0.f);
            h[1] = (_Float16)fmaxf(acc[u][1], 0.f);
            h[2] = (_Float16)fmaxf(acc[u][2], 0.f);
            h[3] = (_Float16)fmaxf(acc[u][3], 0.f);
            *(half4v*)(xcatH + (size_t)(p0 + u) * 96 + cg * 4) = h;
        }
    }
}

// ===========================================================================
// K2: fused_mid — scan_chunks | upsample z1 | upsample z2
// ===========================================================================
__launch_bounds__(1024)
__global__ void fused_mid(const int* __restrict__ cntT,
                          int* __restrict__ scanEx,
                          int* __restrict__ chunkTot,
                          const float* __restrict__ a4s,
                          const float* __restrict__ a32s,
                          _Float16* __restrict__ xcatH) {
    const int blk = blockIdx.x;
    const int t = threadIdx.x;

    if (blk < 81) {
        __shared__ int s[1024];
        const int gi = blk * 1024 + t;
        int v = cntT[gi];
        s[t] = v;
        __syncthreads();
        for (int off = 1; off < 1024; off <<= 1) {
            int x = (t >= off) ? s[t - off] : 0;
            __syncthreads();
            s[t] += x;
            __syncthreads();
        }
        scanEx[gi] = s[t] - v;
        if (t == 1023) chunkTot[blk] = s[t];
        return;
    }

    const int z = (blk < 81 + 576) ? 1 : 2;
    int tt = ((z == 1) ? (blk - 81) : (blk - 657)) * 1024 + t;
    int p = tt >> 3, cg = tt & 7;

    const float* src = (z == 1) ? a4s : a32s;
    const int   S    = (z == 1) ? 96 : 24;
    const float inv  = (z == 1) ? 0.5f : 0.125f;
    const int   coff = (z == 1) ? 32 : 64;

    int x = p % HA;
    int r = p / HA;
    int y = r % HA;
    int b = r / HA;

    float u = ((float)y + 0.5f) * inv - 0.5f;
    float v = ((float)x + 0.5f) * inv - 0.5f;
    float fu = floorf(u), fv = floorf(v);
    float wu = u - fu, wv = v - fv;
    int y0 = (int)fu, x0 = (int)fv;
    int y1 = min(y0 + 1, S - 1);
    int x1 = min(x0 + 1, S - 1);
    y0 = max(y0, 0);
    x0 = max(x0, 0);

    const float* sb = src + (size_t)b * S * S * 32 + cg * 4;
    float4v v00 = *(const float4v*)(sb + (y0 * S + x0) * 32);
    float4v v01 = *(const float4v*)(sb + (y0 * S + x1) * 32);
    float4v v10 = *(const float4v*)(sb + (y1 * S + x0) * 32);
    float4v v11 = *(const float4v*)(sb + (y1 * S + x1) * 32);
    half4v h;
#pragma unroll
    for (int j = 0; j < 4; ++j) {
        float t0 = v00[j] * (1.f - wu) + v10[j] * wu;
        float t1 = v01[j] * (1.f - wu) + v11[j] * wu;
        h[j] = (_Float16)(t0 * (1.f - wv) + t1 * wv);
    }
    *(half4v*)(xcatH + (size_t)p * 96 + coff + cg * 4) = h;
}

// ===========================================================================
// K3: fused_back — conv3x3_mfma | sort_scatter (R15 structure, proven)
// ===========================================================================
__launch_bounds__(256, 4)
__global__ void fused_back(const _Float16* __restrict__ xH,
                           const _Float16* __restrict__ fragTabW,
                           const float* __restrict__ bias,
                           _Float16* __restrict__ yH,
                           const float* __restrict__ coords,
                           const float* __restrict__ cells,
                           const int* __restrict__ scanEx,
                           const int* __restrict__ chunkTot,
                           const unsigned short* __restrict__ lrank,
                           int* __restrict__ qidx,
                           float4v* __restrict__ qdata) {
    __shared__ __align__(16) unsigned char smemU[37440];
    const int blk = blockIdx.x;
    const int tid = threadIdx.x;

    if (blk < 576) {
        _Float16* lds = (_Float16*)smemU;
        const int lane = tid & 63;
        const int wv   = tid >> 6;
        const int n_   = lane & 15;
        const int qd   = lane >> 4;
        const int nh   = wv & 1;
        const int yg   = wv >> 1;
        const int bx0  = (blk % 12) * 16;
        const int by0  = ((blk / 12) % 24) * 8;
        const int b    = blk / 288;

        for (int idx = tid; idx < 2160; idx += 256) {
            int hy  = idx / 216;
            int rem = idx - hy * 216;
            int hx  = rem / 12;
            int cc  = rem - hx * 12;
            int gy = by0 + hy - 1, gx = bx0 + hx - 1;
            half8 v = {(_Float16)0.f, (_Float16)0.f, (_Float16)0.f, (_Float16)0.f,
                       (_Float16)0.f, (_Float16)0.f, (_Float16)0.f, (_Float16)0.f};
            if (gy >= 0 && gy < HA && gx >= 0 && gx < HA)
                v = *(const half8*)(xH + (((size_t)b * HA + gy) * HA + gx) * 96 + cc * 8);
            *(half8*)&lds[(hy * 18 + hx) * 104 + cc * 8] = v;
        }

        float bv[3];
#pragma unroll
        for (int j = 0; j < 3; ++j) bv[j] = bias[(nh * 3 + j) * 16 + n_];

        __syncthreads();

        float4v acc[4][3];
#pragma unroll
        for (int r = 0; r < 4; ++r)
#pragma unroll
            for (int j = 0; j < 3; ++j) {
                float4v z = {0.f, 0.f, 0.f, 0.f};
                acc[r][j] = z;
            }

#pragma unroll 1
        for (int ky = 0; ky < 3; ++ky)
#pragma unroll 1
            for (int kx = 0; kx < 3; ++kx) {
                const int tap = ky * 3 + kx;
#pragma unroll
                for (int kc = 0; kc < 3; ++kc) {
                    const int s = tap * 3 + kc;
                    half8 bf[3];
#pragma unroll
                    for (int j = 0; j < 3; ++j)
                        bf[j] = *(const half8*)(fragTabW +
                                ((size_t)(s * 6 + nh * 3 + j) * 64 + lane) * 8);
#pragma unroll
                    for (int r = 0; r < 4; ++r) {
                        const int yr = yg * 4 + r;
                        half8 a = *(const half8*)&lds[((yr + ky) * 18 + (n_ + kx)) * 104
                                                      + kc * 32 + qd * 8];
#pragma unroll
                        for (int j = 0; j < 3; ++j)
                            acc[r][j] = __builtin_amdgcn_mfma_f32_16x16x32_f16(
                                a, bf[j], acc[r][j], 0, 0, 0);
                    }
                }
            }

#pragma unroll
        for (int r = 0; r < 4; ++r) {
            const int gy = by0 + yg * 4 + r;
#pragma unroll
            for (int j = 0; j < 3; ++j) {
                const int ch = (nh * 3 + j) * 16 + n_;
#pragma unroll
                for (int reg = 0; reg < 4; ++reg) {
                    const int gx = bx0 + qd * 4 + reg;
                    yH[(((size_t)b * HA + gy) * HA + gx) * 96 + ch] =
                        (_Float16)fmaxf(acc[r][j][reg] + bv[j], 0.f);
                }
            }
        }
    } else {
        int* pEx = (int*)smemU;   // 128 ints
        int v = 0;
        if (tid < 81) v = chunkTot[tid];
        if (tid < 128) pEx[tid] = v;
        __syncthreads();
        for (int off = 1; off < 128; off <<= 1) {
            int x = 0;
            if (tid < 128 && tid >= off) x = pEx[tid - off];
            __syncthreads();
            if (tid < 128) pEx[tid] += x;
            __syncthreads();
        }
        if (tid < 128) pEx[tid] -= v;   // inclusive -> exclusive
        __syncthreads();

        const int q = (blk - 576) * 256 + tid;
        float cy = coords[(size_t)q * 2 + 0];
        float cx = coords[(size_t)q * 2 + 1];
        int bkt = bucket_id(q, cy, cx);
        int sb  = q >> 10;
        int li  = bkt * NBS + sb;
        int pos = pEx[li >> 10] + scanEx[li] + (int)lrank[q];
        qidx[pos] = q;
        float4v d = {cy, cx,
                     cells[(size_t)q * 2 + 0] * (float)HA,
                     cells[(size_t)q * 2 + 1] * (float)HA};
        qdata[pos] = d;
    }
}

// ===========================================================================
// K4: decoder — 32x32x16 MFMA, 8 queries/wave, 32-AGPR accumulator (R28).
// ===========================================================================
__launch_bounds__(1024, 8)
__global__ void decoder_mlp_mfma(const _Float16* __restrict__ asppH,
                                 const int* __restrict__ qidx,
                                 const float4v* __restrict__ qdata,
                                 const _Float16* __restrict__ fragTab,
                                 const float* __restrict__ mw2,
                                 const float* __restrict__ mb2,
                                 float* __restrict__ out) {
    __shared__ __align__(16) _Float16 fragL[24 * 64 * 8];  // 24576 B
    __shared__ __align__(16) float biasL[68];

    const int tid  = threadIdx.x;
    const int lane = tid & 63;
    const int wv   = tid >> 6;            // 0..15
    const int h    = lane >> 5;           // k-half
    const int col  = lane & 31;           // query-corner column
    const int R    = (blockIdx.x & 7) * 288 + (blockIdx.x >> 3);

    // ---- per-lane corner data (issued before staging barrier) ----
    const int sp = R * 128 + wv * 8 + (col >> 2);   // global query slot
    const float4v d = qdata[sp];
    const int   qq = qidx[sp];
    const int   b  = qq / (HQ * HQ);
    const float cy = d[0], cx = d[1], rcy = d[2], rcx = d[3];
    const int   k  = col & 3;

    const float LO = -1.0f + 1e-7f, HI = 1.0f - 1e-7f;
    const float RXY = 1.0f / (float)HA;
    const float vy = (k < 2) ? -1.f : 1.f;
    const float vx = (k & 1) ? 1.f : -1.f;

    float c0 = fminf(fmaxf((cy + vy * RXY) + 1e-7f, LO), HI);
    float c1 = fminf(fmaxf((cx + vx * RXY) + 1e-7f, LO), HI);
    int iy = (int)rintf(((c0 + 1.f) * (float)HA) * 0.5f - 0.5f);
    int ix = (int)rintf(((c1 + 1.f) * (float)HA) * 0.5f - 0.5f);
    iy = min(max(iy, 0), HA - 1);
    ix = min(max(ix, 0), HA - 1);

    const float cs0 = (((float)iy + 0.5f) / (float)HA) * 2.f - 1.f;
    const float cs1 = (((float)ix + 0.5f) / (float)HA) * 2.f - 1.f;
    const float r0 = (cy - cs0) * (float)HA;
    const float r1 = (cx - cs1) * (float)HA;
    const float area = fabsf(r0 * r1) + 1e-7f;
    const int   pix = ((b * HA + iy) * HA + ix) * 96;

    // ---- B-operand (features), first 3 K-steps: k = ks*16 + h*8 + j ----
    half8 Xf[3];
    Xf[0] = *(const half8*)(asppH + pix + 0 * 16 + h * 8);
    Xf[1] = *(const half8*)(asppH + pix + 1 * 16 + h * 8);
    Xf[2] = *(const half8*)(asppH + pix + 2 * 16 + h * 8);

    // ---- cooperative staging: fragTab -> fragL (1536 half8), biases ----
#pragma unroll
    for (int it = 0; it < 2; ++it) {
        const int i = it * 1024 + tid;
        if (i < 1536)
            *(half8*)&fragL[i * 8] = *(const half8*)(fragTab + (size_t)i * 8);
    }
    if (tid < 64) biasL[tid] = mw2[tid];
    if (tid == 0) biasL[64] = mb2[0];
    __syncthreads();

    // ---- layer0: acc[nt][reg] = H[col][nt*32 + (reg&3)+8*(reg>>2)+4h] ----
    float16v acc[2];
    {
        float16v z{};
        acc[0] = z;
        acc[1] = z;
    }
#pragma unroll
    for (int ks = 0; ks < 3; ++ks)
#pragma unroll
        for (int nt = 0; nt < 2; ++nt) {
            half8 w0 = *(const half8*)&fragL[((ks * 2 + nt) * 64 + lane) * 8];
            acc[nt] = __builtin_amdgcn_mfma_f32_32x32x16_f16(w0, Xf[ks],
                                                             acc[nt], 0, 0, 0);
        }

    // second feature batch: ks 3..5, then ks=6 = extras + constant-1
    Xf[0] = *(const half8*)(asppH + pix + 3 * 16 + h * 8);
    Xf[1] = *(const half8*)(asppH + pix + 4 * 16 + h * 8);
    Xf[2] = *(const half8*)(asppH + pix + 5 * 16 + h * 8);
#pragma unroll
    for (int ks = 0; ks < 3; ++ks)
#pragma unroll
        for (int nt = 0; nt < 2; ++nt) {
            half8 w0 = *(const half8*)&fragL[(((ks + 3) * 2 + nt) * 64 + lane) * 8];
            acc[nt] = __builtin_amdgcn_mfma_f32_32x32x16_f16(w0, Xf[ks],
                                                             acc[nt], 0, 0, 0);
        }
    {
        half8 e = {(_Float16)0.f, (_Float16)0.f, (_Float16)0.f, (_Float16)0.f,
                   (_Float16)0.f, (_Float16)0.f, (_Float16)0.f, (_Float16)0.f};
        if (h == 0) {
            e[0] = (_Float16)r0;  e[1] = (_Float16)r1;
            e[2] = (_Float16)cy;  e[3] = (_Float16)cx;
            e[4] = (_Float16)rcy; e[5] = (_Float16)rcx;
            e[6] = (_Float16)1.f;   // k=102: constant-1 -> mb0 row
        }
#pragma unroll
        for (int nt = 0; nt < 2; ++nt) {
            half8 w0 = *(const half8*)&fragL[((6 * 2 + nt) * 64 + lane) * 8];
            acc[nt] = __builtin_amdgcn_mfma_f32_32x32x16_f16(w0, e,
                                                             acc[nt], 0, 0, 0);
        }
    }

    // ---- layer1 B fragments straight from accumulators ----
    half8 b1f[5];
#pragma unroll
    for (int ks = 0; ks < 4; ++ks) {
        half8 t;
#pragma unroll
        for (int j = 0; j < 8; ++j)
            t[j] = (_Float16)fmaxf(acc[ks >> 1][(ks & 1) * 8 + j], 0.f);
        b1f[ks] = t;
    }
    {
        half8 e = {(_Float16)0.f, (_Float16)0.f, (_Float16)0.f, (_Float16)0.f,
                   (_Float16)0.f, (_Float16)0.f, (_Float16)0.f, (_Float16)0.f};
        if (h == 0) e[0] = (_Float16)1.f;   // k=64: constant-1 -> mb1 row
        b1f[4] = e;
    }

    // ---- layer1: 10 MFMAs ----
    float16v acc1[2];
    {
        float16v z{};
        acc1[0] = z;
        acc1[1] = z;
    }
#pragma unroll
    for (int ks = 0; ks < 5; ++ks)
#pragma unroll
        for (int nt = 0; nt < 2; ++nt) {
            half8 w1 = *(const half8*)&fragL[(((14 + ks * 2 + nt)) * 64 + lane) * 8];
            acc1[nt] = __builtin_amdgcn_mfma_f32_32x32x16_f16(w1, b1f[ks],
                                                              acc1[nt], 0, 0, 0);
        }

    // ---- layer2: lane dots its 32 neurons, partner-half via xor 32 ----
    float s = 0.f;
#pragma unroll
    for (int nt = 0; nt < 2; ++nt)
#pragma unroll
        for (int q = 0; q < 4; ++q) {
            float4v w2v = *(const float4v*)&biasL[nt * 32 + q * 8 + h * 4];
#pragma unroll
            for (int i = 0; i < 4; ++i)
                s = fmaf(fmaxf(acc1[nt][q * 4 + i], 0.f), w2v[i], s);
        }
    s += __shfl_xor(s, 32, 64);
    const float p = s + biasL[64];

    // ---- 4-corner combine: corner k = col&3, opposite = col^3 ----
    float a_opp = __shfl_xor(area, 3, 64);
    float np = p * a_opp;
    float dp = area;
    np += __shfl_xor(np, 1, 64);
    dp += __shfl_xor(dp, 1, 64);
    np += __shfl_xor(np, 2, 64);
    dp += __shfl_xor(dp, 2, 64);

    if ((lane & 0x23) == 0)   // h==0 && corner==0: lanes 0,4,...,28
        out[qq] = np / dp;
}

// ---------------------------------------------------------------------------
extern "C" void kernel_launch(void* const* d_in, const int* in_sizes, int n_in,
                              void* d_out, int out_size, void* d_ws, size_t ws_size,
                              hipStream_t stream) {
    (void)in_sizes; (void)n_in; (void)out_size; (void)ws_size;
    const float* feats2  = (const float*)d_in[0];
    const float* feats4  = (const float*)d_in[1];
    const float* feats32 = (const float*)d_in[2];
    const float* coords  = (const float*)d_in[3];
    const float* cells   = (const float*)d_in[4];
    const float* w2  = (const float*)d_in[5];
    const float* b2  = (const float*)d_in[6];
    const float* w4  = (const float*)d_in[7];
    const float* b4  = (const float*)d_in[8];
    const float* w32 = (const float*)d_in[9];
    const float* b32 = (const float*)d_in[10];
    const float* wf  = (const float*)d_in[11];
    const float* bf  = (const float*)d_in[12];
    const float* mw0 = (const float*)d_in[13];
    const float* mb0 = (const float*)d_in[14];
    const float* mw1 = (const float*)d_in[15];
    const float* mb1 = (const float*)d_in[16];
    const float* mw2 = (const float*)d_in[17];
    const float* mb2 = (const float*)d_in[18];

    float* ws = (float*)d_ws;
    float*    a4s   = ws;                          // 589824 f
    float*    a32s  = a4s + 589824;                // 36864 f
    _Float16* xcatH = (_Float16*)(a32s + 36864);   // 7,077,888 h
    _Float16* asppH = xcatH + 7077888;             // 7,077,888 h
    _Float16* fragTab  = asppH + 7077888;          // 12,288 h
    _Float16* fragTabW = fragTab + 12288;          // 82,944 h
    float4v*  qdata = (float4v*)(fragTabW + 82944);   // NQ * 16 B
    int*      qidx  = (int*)(qdata + NQ);             // NQ ints
    int*      cntT  = qidx + NQ;                      // NFLAT ints
    int*      scanEx = cntT + NFLAT;                  // NFLAT ints
    int*      chunkTot = scanEx + NFLAT;              // 81 ints (pad 128)
    unsigned short* lrank = (unsigned short*)(chunkTot + 128);  // NQ u16
    float* out = (float*)d_out;

    fused_front<<<483, 1024, 0, stream>>>(coords, cntT, lrank,
                                          mw0, mb0, mw1, mb1, wf,
                                          fragTab, fragTabW,
                                          feats4, w4, b4, feats32, w32, b32,
                                          a4s, a32s, feats2, w2, b2, xcatH);
    fused_mid<<<1233, 1024, 0, stream>>>(cntT, scanEx, chunkTot,
                                         a4s, a32s, xcatH);
    fused_back<<<1728, 256, 0, stream>>>(xcatH, fragTabW, bf, asppH,
                                         coords, cells, scanEx, chunkTot,
                                         lrank, qidx, qdata);
    decoder_mlp_mfma<<<2304, 1024, 0, stream>>>(asppH, qidx, qdata, fragTab,
                                                mw2, mb2, out);
}

// Round 11
// 191.242 us; speedup vs baseline: 1.0399x; 1.0399x over previous
//
#include <hip/hip_runtime.h>
#include <math.h>

// ---------------------------------------------------------------------------
// Decoder_82764019794508: LIIF-style decoder.
// R30: revert fused_front conv paths to R28's 1-px/thread (grid 1029).
// R29's 4-px/thread "issue diet" quadrupled FETCH (14.6->60MB): per-(i4,u)
// step a wave touched 32 pixel rows at 1KB stride instead of 8 contiguous
// ones -> L1/L2 thrash; the weight re-loads it removed were free broadcast
// L1 hits. Session best = R28 (193.1us): 32x32x16 decoder (8 q/wave,
// 32-AGPR acc, W1 row-permuted, biases MFMA-folded), R20 front/mid/back.
// This text = R28 verbatim.
// ---------------------------------------------------------------------------

#define HQ 384
#define HA 192
#define NQ (2 * HQ * HQ)   // 294912 queries
#define NBS (NQ / 1024)    // 288 sort blocks (1024 threads each)
#define NBKT 288           // 2 batches x 12x12 tiles of 16x16 px
#define NFLAT (NBKT * NBS) // 82944 = 81 * 1024

typedef _Float16 half8  __attribute__((ext_vector_type(8)));
typedef _Float16 half4v __attribute__((ext_vector_type(4)));
typedef float    float4v __attribute__((ext_vector_type(4)));
typedef float    float16v __attribute__((ext_vector_type(16)));

// bucket id from query coords: corner k=0 (vy=vx=-1) pixel, 16x16 tiles
__device__ __forceinline__ int bucket_id(int q, float cy, float cx) {
    const float LO = -1.0f + 1e-7f, HI = 1.0f - 1e-7f;
    const float RXY = 1.0f / (float)HA;
    float c0 = fminf(fmaxf((cy - RXY) + 1e-7f, LO), HI);
    float c1 = fminf(fmaxf((cx - RXY) + 1e-7f, LO), HI);
    int iy = (int)rintf(((c0 + 1.f) * (float)HA) * 0.5f - 0.5f);
    int ix = (int)rintf(((c1 + 1.f) * (float)HA) * 0.5f - 0.5f);
    iy = min(max(iy, 0), HA - 1);
    ix = min(max(ix, 0), HA - 1);
    int b = q / (HQ * HQ);
    return b * 144 + (iy >> 4) * 12 + (ix >> 4);
}

// ===========================================================================
// K1: fused_front — sort_count | prep frags (32x32 tables) | conv1x1 | xcat
// ===========================================================================
__launch_bounds__(1024)
__global__ void fused_front(const float* __restrict__ coords,
                            int* __restrict__ cntT,
                            unsigned short* __restrict__ lrank,
                            const float* __restrict__ mw0,
                            const float* __restrict__ mb0f,
                            const float* __restrict__ mw1,
                            const float* __restrict__ mb1f,
                            const float* __restrict__ wf,
                            _Float16* __restrict__ fragTab,
                            _Float16* __restrict__ fragTabW,
                            const float* __restrict__ feats4,
                            const float* __restrict__ w4,
                            const float* __restrict__ b4,
                            const float* __restrict__ feats32,
                            const float* __restrict__ w32,
                            const float* __restrict__ b32,
                            float* __restrict__ a4s,
                            float* __restrict__ a32s,
                            const float* __restrict__ feats2,
                            const float* __restrict__ w2,
                            const float* __restrict__ b2,
                            _Float16* __restrict__ xcatH) {
    const int blk = blockIdx.x;
    const int tid = threadIdx.x;

    if (blk < 288) {
        __shared__ int lh[NBKT];
        if (tid < NBKT) lh[tid] = 0;
        __syncthreads();
        const int q = blk * 1024 + tid;
        float cy = coords[(size_t)q * 2 + 0];
        float cx = coords[(size_t)q * 2 + 1];
        int r = atomicAdd(&lh[bucket_id(q, cy, cx)], 1);
        lrank[q] = (unsigned short)r;
        __syncthreads();
        if (tid < NBKT) cntT[tid * NBS + blk] = lh[tid];
    } else if (blk < 300) {
        int t = (blk - 288) * 1024 + tid;
        if (t < 1536) {
            // 24 fragments x 64 lanes: f 0..13 = W0 (ks 0..6, nt 0..1),
            // f 14..23 = W1 (ks 0..4, nt 0..1). A-operand layout for
            // 32x32x16: row = lane&31, k = (lane>>5)*8 + j.
            int f = t >> 6, L = t & 63;
            int h = L >> 5;
            _Float16 vals[8];
            if (f < 14) {
                int ks = f >> 1, nt = f & 1;
                int col = nt * 32 + (L & 31);
#pragma unroll
                for (int j = 0; j < 8; ++j) {
                    int kk = ks * 16 + h * 8 + j;
                    float v = (kk < 102) ? mw0[kk * 64 + col]
                            : ((kk == 102) ? mb0f[col] : 0.f);
                    vals[j] = (_Float16)v;
                }
            } else {
                // W1 with ROW PERMUTATION: physical k-slot kp holds logical
                // row n = kp with bits 3<->2 swapped, so layer1 B-frags are
                // b1[ks][j] = relu(acc[ks>>1][(ks&1)*8+j]) straight from the
                // layer0 accumulator. ks=4 (k 64..79): row 64 = mb1, rest 0.
                int g = f - 14;
                int ks = g >> 1, nt = g & 1;
                int col = nt * 32 + (L & 31);
#pragma unroll
                for (int j = 0; j < 8; ++j) {
                    int kp = ks * 16 + h * 8 + j;
                    float v;
                    if (ks < 4) {
                        int n = (kp & 0x33) | ((kp & 8) >> 1) | ((kp & 4) << 1);
                        v = mw1[n * 64 + col];
                    } else {
                        v = (kp == 64) ? mb1f[col] : 0.f;
                    }
                    vals[j] = (_Float16)v;
                }
            }
#pragma unroll
            for (int j = 0; j < 8; ++j) fragTab[t * 8 + j] = vals[j];
        } else {
            int tw = t - 1536;
            if (tw < 27 * 6 * 64) {
                int s   = tw / 384;
                int rem = tw - s * 384;
                int nt  = rem >> 6;
                int L   = rem & 63;
                int n_  = L & 15, qd = L >> 4;
                int tap = s / 3, kc = s - tap * 3;
#pragma unroll
                for (int j = 0; j < 8; ++j) {
                    int kch = kc * 32 + qd * 8 + j;
                    fragTabW[tw * 8 + j] =
                        (_Float16)wf[(tap * 96 + kch) * 96 + nt * 16 + n_];
                }
            }
        }
    } else if (blk < 444) {
        int t = (blk - 300) * 1024 + tid;
        int p = t >> 3, cg = t & 7;
        const float4v* xr = (const float4v*)(feats4 + (size_t)p * 96);
        float4v acc = *(const float4v*)(b4 + cg * 4);
#pragma unroll
        for (int i4 = 0; i4 < 24; ++i4) {
            float4v xv = xr[i4];
            const float* wr = w4 + (i4 * 4) * 32 + cg * 4;
#pragma unroll
            for (int j = 0; j < 4; ++j) {
                float4v wv = *(const float4v*)(wr + j * 32);
                acc[0] = fmaf(xv[j], wv[0], acc[0]);
                acc[1] = fmaf(xv[j], wv[1], acc[1]);
                acc[2] = fmaf(xv[j], wv[2], acc[2]);
                acc[3] = fmaf(xv[j], wv[3], acc[3]);
            }
        }
        float4v o = {fmaxf(acc[0], 0.f), fmaxf(acc[1], 0.f),
                     fmaxf(acc[2], 0.f), fmaxf(acc[3], 0.f)};
        *(float4v*)(a4s + (size_t)p * 32 + cg * 4) = o;
    } else if (blk < 453) {
        int t = (blk - 444) * 1024 + tid;
        if (t >= 1152 * 8) return;
        int p = t >> 3, cg = t & 7;
        const float4v* xr = (const float4v*)(feats32 + (size_t)p * 160);
        float4v acc = *(const float4v*)(b32 + cg * 4);
#pragma unroll
        for (int i4 = 0; i4 < 40; ++i4) {
            float4v xv = xr[i4];
            const float* wr = w32 + (i4 * 4) * 32 + cg * 4;
#pragma unroll
            for (int j = 0; j < 4; ++j) {
                float4v wv = *(const float4v*)(wr + j * 32);
                acc[0] = fmaf(xv[j], wv[0], acc[0]);
                acc[1] = fmaf(xv[j], wv[1], acc[1]);
                acc[2] = fmaf(xv[j], wv[2], acc[2]);
                acc[3] = fmaf(xv[j], wv[3], acc[3]);
            }
        }
        float4v o = {fmaxf(acc[0], 0.f), fmaxf(acc[1], 0.f),
                     fmaxf(acc[2], 0.f), fmaxf(acc[3], 0.f)};
        *(float4v*)(a32s + (size_t)p * 32 + cg * 4) = o;
    } else {
        int t = (blk - 453) * 1024 + tid;
        int p = t >> 3, cg = t & 7;
        const float4v* xr = (const float4v*)(feats2 + (size_t)p * 64);
        float4v acc = *(const float4v*)(b2 + cg * 4);
#pragma unroll
        for (int i4 = 0; i4 < 16; ++i4) {
            float4v xv = xr[i4];
            const float* wr = w2 + (i4 * 4) * 32 + cg * 4;
#pragma unroll
            for (int j = 0; j < 4; ++j) {
                float4v wv = *(const float4v*)(wr + j * 32);
                acc[0] = fmaf(xv[j], wv[0], acc[0]);
                acc[1] = fmaf(xv[j], wv[1], acc[1]);
                acc[2] = fmaf(xv[j], wv[2], acc[2]);
                acc[3] = fmaf(xv[j], wv[3], acc[3]);
            }
        }
        half4v h;
        h[0] = (_Float16)fmaxf(acc[0], 0.f);
        h[1] = (_Float16)fmaxf(acc[1], 0.f);
        h[2] = (_Float16)fmaxf(acc[2], 0.f);
        h[3] = (_Float16)fmaxf(acc[3], 0.f);
        *(half4v*)(xcatH + (size_t)p * 96 + cg * 4) = h;
    }
}

// ===========================================================================
// K2: fused_mid — scan_chunks | upsample z1 | upsample z2
// ===========================================================================
__launch_bounds__(1024)
__global__ void fused_mid(const int* __restrict__ cntT,
                          int* __restrict__ scanEx,
                          int* __restrict__ chunkTot,
                          const float* __restrict__ a4s,
                          const float* __restrict__ a32s,
                          _Float16* __restrict__ xcatH) {
    const int blk = blockIdx.x;
    const int t = threadIdx.x;

    if (blk < 81) {
        __shared__ int s[1024];
        const int gi = blk * 1024 + t;
        int v = cntT[gi];
        s[t] = v;
        __syncthreads();
        for (int off = 1; off < 1024; off <<= 1) {
            int x = (t >= off) ? s[t - off] : 0;
            __syncthreads();
            s[t] += x;
            __syncthreads();
        }
        scanEx[gi] = s[t] - v;
        if (t == 1023) chunkTot[blk] = s[t];
        return;
    }

    const int z = (blk < 81 + 576) ? 1 : 2;
    int tt = ((z == 1) ? (blk - 81) : (blk - 657)) * 1024 + t;
    int p = tt >> 3, cg = tt & 7;

    const float* src = (z == 1) ? a4s : a32s;
    const int   S    = (z == 1) ? 96 : 24;
    const float inv  = (z == 1) ? 0.5f : 0.125f;
    const int   coff = (z == 1) ? 32 : 64;

    int x = p % HA;
    int r = p / HA;
    int y = r % HA;
    int b = r / HA;

    float u = ((float)y + 0.5f) * inv - 0.5f;
    float v = ((float)x + 0.5f) * inv - 0.5f;
    float fu = floorf(u), fv = floorf(v);
    float wu = u - fu, wv = v - fv;
    int y0 = (int)fu, x0 = (int)fv;
    int y1 = min(y0 + 1, S - 1);
    int x1 = min(x0 + 1, S - 1);
    y0 = max(y0, 0);
    x0 = max(x0, 0);

    const float* sb = src + (size_t)b * S * S * 32 + cg * 4;
    float4v v00 = *(const float4v*)(sb + (y0 * S + x0) * 32);
    float4v v01 = *(const float4v*)(sb + (y0 * S + x1) * 32);
    float4v v10 = *(const float4v*)(sb + (y1 * S + x0) * 32);
    float4v v11 = *(const float4v*)(sb + (y1 * S + x1) * 32);
    half4v h;
#pragma unroll
    for (int j = 0; j < 4; ++j) {
        float t0 = v00[j] * (1.f - wu) + v10[j] * wu;
        float t1 = v01[j] * (1.f - wu) + v11[j] * wu;
        h[j] = (_Float16)(t0 * (1.f - wv) + t1 * wv);
    }
    *(half4v*)(xcatH + (size_t)p * 96 + coff + cg * 4) = h;
}

// ===========================================================================
// K3: fused_back — conv3x3_mfma | sort_scatter (R15 structure, proven)
// ===========================================================================
__launch_bounds__(256, 4)
__global__ void fused_back(const _Float16* __restrict__ xH,
                           const _Float16* __restrict__ fragTabW,
                           const float* __restrict__ bias,
                           _Float16* __restrict__ yH,
                           const float* __restrict__ coords,
                           const float* __restrict__ cells,
                           const int* __restrict__ scanEx,
                           const int* __restrict__ chunkTot,
                           const unsigned short* __restrict__ lrank,
                           int* __restrict__ qidx,
                           float4v* __restrict__ qdata) {
    __shared__ __align__(16) unsigned char smemU[37440];
    const int blk = blockIdx.x;
    const int tid = threadIdx.x;

    if (blk < 576) {
        _Float16* lds = (_Float16*)smemU;
        const int lane = tid & 63;
        const int wv   = tid >> 6;
        const int n_   = lane & 15;
        const int qd   = lane >> 4;
        const int nh   = wv & 1;
        const int yg   = wv >> 1;
        const int bx0  = (blk % 12) * 16;
        const int by0  = ((blk / 12) % 24) * 8;
        const int b    = blk / 288;

        for (int idx = tid; idx < 2160; idx += 256) {
            int hy  = idx / 216;
            int rem = idx - hy * 216;
            int hx  = rem / 12;
            int cc  = rem - hx * 12;
            int gy = by0 + hy - 1, gx = bx0 + hx - 1;
            half8 v = {(_Float16)0.f, (_Float16)0.f, (_Float16)0.f, (_Float16)0.f,
                       (_Float16)0.f, (_Float16)0.f, (_Float16)0.f, (_Float16)0.f};
            if (gy >= 0 && gy < HA && gx >= 0 && gx < HA)
                v = *(const half8*)(xH + (((size_t)b * HA + gy) * HA + gx) * 96 + cc * 8);
            *(half8*)&lds[(hy * 18 + hx) * 104 + cc * 8] = v;
        }

        float bv[3];
#pragma unroll
        for (int j = 0; j < 3; ++j) bv[j] = bias[(nh * 3 + j) * 16 + n_];

        __syncthreads();

        float4v acc[4][3];
#pragma unroll
        for (int r = 0; r < 4; ++r)
#pragma unroll
            for (int j = 0; j < 3; ++j) {
                float4v z = {0.f, 0.f, 0.f, 0.f};
                acc[r][j] = z;
            }

#pragma unroll 1
        for (int ky = 0; ky < 3; ++ky)
#pragma unroll 1
            for (int kx = 0; kx < 3; ++kx) {
                const int tap = ky * 3 + kx;
#pragma unroll
                for (int kc = 0; kc < 3; ++kc) {
                    const int s = tap * 3 + kc;
                    half8 bf[3];
#pragma unroll
                    for (int j = 0; j < 3; ++j)
                        bf[j] = *(const half8*)(fragTabW +
                                ((size_t)(s * 6 + nh * 3 + j) * 64 + lane) * 8);
#pragma unroll
                    for (int r = 0; r < 4; ++r) {
                        const int yr = yg * 4 + r;
                        half8 a = *(const half8*)&lds[((yr + ky) * 18 + (n_ + kx)) * 104
                                                      + kc * 32 + qd * 8];
#pragma unroll
                        for (int j = 0; j < 3; ++j)
                            acc[r][j] = __builtin_amdgcn_mfma_f32_16x16x32_f16(
                                a, bf[j], acc[r][j], 0, 0, 0);
                    }
                }
            }

#pragma unroll
        for (int r = 0; r < 4; ++r) {
            const int gy = by0 + yg * 4 + r;
#pragma unroll
            for (int j = 0; j < 3; ++j) {
                const int ch = (nh * 3 + j) * 16 + n_;
#pragma unroll
                for (int reg = 0; reg < 4; ++reg) {
                    const int gx = bx0 + qd * 4 + reg;
                    yH[(((size_t)b * HA + gy) * HA + gx) * 96 + ch] =
                        (_Float16)fmaxf(acc[r][j][reg] + bv[j], 0.f);
                }
            }
        }
    } else {
        int* pEx = (int*)smemU;   // 128 ints
        int v = 0;
        if (tid < 81) v = chunkTot[tid];
        if (tid < 128) pEx[tid] = v;
        __syncthreads();
        for (int off = 1; off < 128; off <<= 1) {
            int x = 0;
            if (tid < 128 && tid >= off) x = pEx[tid - off];
            __syncthreads();
            if (tid < 128) pEx[tid] += x;
            __syncthreads();
        }
        if (tid < 128) pEx[tid] -= v;   // inclusive -> exclusive
        __syncthreads();

        const int q = (blk - 576) * 256 + tid;
        float cy = coords[(size_t)q * 2 + 0];
        float cx = coords[(size_t)q * 2 + 1];
        int bkt = bucket_id(q, cy, cx);
        int sb  = q >> 10;
        int li  = bkt * NBS + sb;
        int pos = pEx[li >> 10] + scanEx[li] + (int)lrank[q];
        qidx[pos] = q;
        float4v d = {cy, cx,
                     cells[(size_t)q * 2 + 0] * (float)HA,
                     cells[(size_t)q * 2 + 1] * (float)HA};
        qdata[pos] = d;
    }
}

// ===========================================================================
// K4: decoder — 32x32x16 MFMA, 8 queries/wave, 32-AGPR accumulator (R28).
// col = lane&31 = query-corner (query g=col>>2, corner k=col&3);
// h = lane>>5 selects the k-half of each 16-wide K-step.
// LDS: fragL 24.6KB + bias 0.3KB; grid 2304 x 1024.
// ===========================================================================
__launch_bounds__(1024, 8)
__global__ void decoder_mlp_mfma(const _Float16* __restrict__ asppH,
                                 const int* __restrict__ qidx,
                                 const float4v* __restrict__ qdata,
                                 const _Float16* __restrict__ fragTab,
                                 const float* __restrict__ mw2,
                                 const float* __restrict__ mb2,
                                 float* __restrict__ out) {
    __shared__ __align__(16) _Float16 fragL[24 * 64 * 8];  // 24576 B
    __shared__ __align__(16) float biasL[68];

    const int tid  = threadIdx.x;
    const int lane = tid & 63;
    const int wv   = tid >> 6;            // 0..15
    const int h    = lane >> 5;           // k-half
    const int col  = lane & 31;           // query-corner column
    const int R    = (blockIdx.x & 7) * 288 + (blockIdx.x >> 3);

    // ---- per-lane corner data (issued before staging barrier) ----
    const int sp = R * 128 + wv * 8 + (col >> 2);   // global query slot
    const float4v d = qdata[sp];
    const int   qq = qidx[sp];
    const int   b  = qq / (HQ * HQ);
    const float cy = d[0], cx = d[1], rcy = d[2], rcx = d[3];
    const int   k  = col & 3;

    const float LO = -1.0f + 1e-7f, HI = 1.0f - 1e-7f;
    const float RXY = 1.0f / (float)HA;
    const float vy = (k < 2) ? -1.f : 1.f;
    const float vx = (k & 1) ? 1.f : -1.f;

    float c0 = fminf(fmaxf((cy + vy * RXY) + 1e-7f, LO), HI);
    float c1 = fminf(fmaxf((cx + vx * RXY) + 1e-7f, LO), HI);
    int iy = (int)rintf(((c0 + 1.f) * (float)HA) * 0.5f - 0.5f);
    int ix = (int)rintf(((c1 + 1.f) * (float)HA) * 0.5f - 0.5f);
    iy = min(max(iy, 0), HA - 1);
    ix = min(max(ix, 0), HA - 1);

    const float cs0 = (((float)iy + 0.5f) / (float)HA) * 2.f - 1.f;
    const float cs1 = (((float)ix + 0.5f) / (float)HA) * 2.f - 1.f;
    const float r0 = (cy - cs0) * (float)HA;
    const float r1 = (cx - cs1) * (float)HA;
    const float area = fabsf(r0 * r1) + 1e-7f;
    const int   pix = ((b * HA + iy) * HA + ix) * 96;

    // ---- B-operand (features), first 3 K-steps: k = ks*16 + h*8 + j ----
    half8 Xf[3];
    Xf[0] = *(const half8*)(asppH + pix + 0 * 16 + h * 8);
    Xf[1] = *(const half8*)(asppH + pix + 1 * 16 + h * 8);
    Xf[2] = *(const half8*)(asppH + pix + 2 * 16 + h * 8);

    // ---- cooperative staging: fragTab -> fragL (1536 half8), biases ----
#pragma unroll
    for (int it = 0; it < 2; ++it) {
        const int i = it * 1024 + tid;
        if (i < 1536)
            *(half8*)&fragL[i * 8] = *(const half8*)(fragTab + (size_t)i * 8);
    }
    if (tid < 64) biasL[tid] = mw2[tid];
    if (tid == 0) biasL[64] = mb2[0];
    __syncthreads();

    // ---- layer0: acc[nt][reg] = H[col][nt*32 + (reg&3)+8*(reg>>2)+4h] ----
    float16v acc[2];
    {
        float16v z{};
        acc[0] = z;
        acc[1] = z;
    }
#pragma unroll
    for (int ks = 0; ks < 3; ++ks)
#pragma unroll
        for (int nt = 0; nt < 2; ++nt) {
            half8 w0 = *(const half8*)&fragL[((ks * 2 + nt) * 64 + lane) * 8];
            acc[nt] = __builtin_amdgcn_mfma_f32_32x32x16_f16(w0, Xf[ks],
                                                             acc[nt], 0, 0, 0);
        }

    // second feature batch: ks 3..5, then ks=6 = extras + constant-1
    Xf[0] = *(const half8*)(asppH + pix + 3 * 16 + h * 8);
    Xf[1] = *(const half8*)(asppH + pix + 4 * 16 + h * 8);
    Xf[2] = *(const half8*)(asppH + pix + 5 * 16 + h * 8);
#pragma unroll
    for (int ks = 0; ks < 3; ++ks)
#pragma unroll
        for (int nt = 0; nt < 2; ++nt) {
            half8 w0 = *(const half8*)&fragL[(((ks + 3) * 2 + nt) * 64 + lane) * 8];
            acc[nt] = __builtin_amdgcn_mfma_f32_32x32x16_f16(w0, Xf[ks],
                                                             acc[nt], 0, 0, 0);
        }
    {
        half8 e = {(_Float16)0.f, (_Float16)0.f, (_Float16)0.f, (_Float16)0.f,
                   (_Float16)0.f, (_Float16)0.f, (_Float16)0.f, (_Float16)0.f};
        if (h == 0) {
            e[0] = (_Float16)r0;  e[1] = (_Float16)r1;
            e[2] = (_Float16)cy;  e[3] = (_Float16)cx;
            e[4] = (_Float16)rcy; e[5] = (_Float16)rcx;
            e[6] = (_Float16)1.f;   // k=102: constant-1 -> mb0 row
        }
#pragma unroll
        for (int nt = 0; nt < 2; ++nt) {
            half8 w0 = *(const half8*)&fragL[((6 * 2 + nt) * 64 + lane) * 8];
            acc[nt] = __builtin_amdgcn_mfma_f32_32x32x16_f16(w0, e,
                                                             acc[nt], 0, 0, 0);
        }
    }

    // ---- layer1 B fragments straight from accumulators ----
    half8 b1f[5];
#pragma unroll
    for (int ks = 0; ks < 4; ++ks) {
        half8 t;
#pragma unroll
        for (int j = 0; j < 8; ++j)
            t[j] = (_Float16)fmaxf(acc[ks >> 1][(ks & 1) * 8 + j], 0.f);
        b1f[ks] = t;
    }
    {
        half8 e = {(_Float16)0.f, (_Float16)0.f, (_Float16)0.f, (_Float16)0.f,
                   (_Float16)0.f, (_Float16)0.f, (_Float16)0.f, (_Float16)0.f};
        if (h == 0) e[0] = (_Float16)1.f;   // k=64: constant-1 -> mb1 row
        b1f[4] = e;
    }

    // ---- layer1: 10 MFMAs ----
    float16v acc1[2];
    {
        float16v z{};
        acc1[0] = z;
        acc1[1] = z;
    }
#pragma unroll
    for (int ks = 0; ks < 5; ++ks)
#pragma unroll
        for (int nt = 0; nt < 2; ++nt) {
            half8 w1 = *(const half8*)&fragL[(((14 + ks * 2 + nt)) * 64 + lane) * 8];
            acc1[nt] = __builtin_amdgcn_mfma_f32_32x32x16_f16(w1, b1f[ks],
                                                              acc1[nt], 0, 0, 0);
        }

    // ---- layer2: lane dots its 32 neurons, partner-half via xor 32 ----
    float s = 0.f;
#pragma unroll
    for (int nt = 0; nt < 2; ++nt)
#pragma unroll
        for (int q = 0; q < 4; ++q) {
            float4v w2v = *(const float4v*)&biasL[nt * 32 + q * 8 + h * 4];
#pragma unroll
            for (int i = 0; i < 4; ++i)
                s = fmaf(fmaxf(acc1[nt][q * 4 + i], 0.f), w2v[i], s);
        }
    s += __shfl_xor(s, 32, 64);
    const float p = s + biasL[64];

    // ---- 4-corner combine: corner k = col&3, opposite = col^3 ----
    float a_opp = __shfl_xor(area, 3, 64);
    float np = p * a_opp;
    float dp = area;
    np += __shfl_xor(np, 1, 64);
    dp += __shfl_xor(dp, 1, 64);
    np += __shfl_xor(np, 2, 64);
    dp += __shfl_xor(dp, 2, 64);

    if ((lane & 0x23) == 0)   // h==0 && corner==0: lanes 0,4,...,28
        out[qq] = np / dp;
}

// ---------------------------------------------------------------------------
extern "C" void kernel_launch(void* const* d_in, const int* in_sizes, int n_in,
                              void* d_out, int out_size, void* d_ws, size_t ws_size,
                              hipStream_t stream) {
    (void)in_sizes; (void)n_in; (void)out_size; (void)ws_size;
    const float* feats2  = (const float*)d_in[0];
    const float* feats4  = (const float*)d_in[1];
    const float* feats32 = (const float*)d_in[2];
    const float* coords  = (const float*)d_in[3];
    const float* cells   = (const float*)d_in[4];
    const float* w2  = (const float*)d_in[5];
    const float* b2  = (const float*)d_in[6];
    const float* w4  = (const float*)d_in[7];
    const float* b4  = (const float*)d_in[8];
    const float* w32 = (const float*)d_in[9];
    const float* b32 = (const float*)d_in[10];
    const float* wf  = (const float*)d_in[11];
    const float* bf  = (const float*)d_in[12];
    const float* mw0 = (const float*)d_in[13];
    const float* mb0 = (const float*)d_in[14];
    const float* mw1 = (const float*)d_in[15];
    const float* mb1 = (const float*)d_in[16];
    const float* mw2 = (const float*)d_in[17];
    const float* mb2 = (const float*)d_in[18];

    float* ws = (float*)d_ws;
    float*    a4s   = ws;                          // 589824 f
    float*    a32s  = a4s + 589824;                // 36864 f
    _Float16* xcatH = (_Float16*)(a32s + 36864);   // 7,077,888 h
    _Float16* asppH = xcatH + 7077888;             // 7,077,888 h
    _Float16* fragTab  = asppH + 7077888;          // 12,288 h
    _Float16* fragTabW = fragTab + 12288;          // 82,944 h
    float4v*  qdata = (float4v*)(fragTabW + 82944);   // NQ * 16 B
    int*      qidx  = (int*)(qdata + NQ);             // NQ ints
    int*      cntT  = qidx + NQ;                      // NFLAT ints
    int*      scanEx = cntT + NFLAT;                  // NFLAT ints
    int*      chunkTot = scanEx + NFLAT;              // 81 ints (pad 128)
    unsigned short* lrank = (unsigned short*)(chunkTot + 128);  // NQ u16
    float* out = (float*)d_out;

    fused_front<<<1029, 1024, 0, stream>>>(coords, cntT, lrank,
                                           mw0, mb0, mw1, mb1, wf,
                                           fragTab, fragTabW,
                                           feats4, w4, b4, feats32, w32, b32,
                                           a4s, a32s, feats2, w2, b2, xcatH);
    fused_mid<<<1233, 1024, 0, stream>>>(cntT, scanEx, chunkTot,
                                         a4s, a32s, xcatH);
    fused_back<<<1728, 256, 0, stream>>>(xcatH, fragTabW, bf, asppH,
                                         coords, cells, scanEx, chunkTot,
                                         lrank, qidx, qdata);
    decoder_mlp_mfma<<<2304, 1024, 0, stream>>>(asppH, qidx, qdata, fragTab,
                                                mw2, mb2, out);
}